// Round 1
// baseline (839.126 us; speedup 1.0000x reference)
//
#include <hip/hip_runtime.h>
#include <math.h>

#define B_  2
#define T_  2048
#define C_  1024
#define H_  16
#define HD_ 64
#define F3_ 3072   // 3*C

// ---------------------------------------------------------------------------
// GEMM (B-transposed weights): C[m][n] = sum_k A[m][k] * Bm[n][k]
// fp32 baseline: 64x64 tile, BK=32, 256 threads, 4x4 micro-tile.
// ---------------------------------------------------------------------------
__global__ __launch_bounds__(256) void gemm_bt_f32(const float* __restrict__ A,
                                                   const float* __restrict__ Bm,
                                                   float* __restrict__ C,
                                                   int M, int N, int K) {
  __shared__ float As[32][68];  // As[k][m], pad 68 to soften store conflicts
  __shared__ float Bs[32][68];  // Bs[k][n]
  const int tid = threadIdx.x;
  const int m0 = blockIdx.x * 64;
  const int n0 = blockIdx.y * 64;
  const int tx = tid & 15;      // -> n micro
  const int ty = tid >> 4;      // -> m micro
  float acc[4][4] = {};

  for (int k0 = 0; k0 < K; k0 += 32) {
    // stage A,B tiles (64 rows x 32 k) as [k][row]
#pragma unroll
    for (int rep = 0; rep < 2; ++rep) {
      int idx = rep * 256 + tid;       // 0..511
      int r   = idx >> 3;              // 0..63
      int kc  = (idx & 7) << 2;        // 0,4,...,28
      float4 a = *(const float4*)(A + (size_t)(m0 + r) * K + k0 + kc);
      As[kc + 0][r] = a.x; As[kc + 1][r] = a.y;
      As[kc + 2][r] = a.z; As[kc + 3][r] = a.w;
      float4 b = *(const float4*)(Bm + (size_t)(n0 + r) * K + k0 + kc);
      Bs[kc + 0][r] = b.x; Bs[kc + 1][r] = b.y;
      Bs[kc + 2][r] = b.z; Bs[kc + 3][r] = b.w;
    }
    __syncthreads();
#pragma unroll 8
    for (int k = 0; k < 32; ++k) {
      float4 ra = *(const float4*)&As[k][ty * 4];
      float4 rb = *(const float4*)&Bs[k][tx * 4];
      float am[4] = {ra.x, ra.y, ra.z, ra.w};
      float bn[4] = {rb.x, rb.y, rb.z, rb.w};
#pragma unroll
      for (int i = 0; i < 4; ++i)
#pragma unroll
        for (int j = 0; j < 4; ++j) acc[i][j] += am[i] * bn[j];
    }
    __syncthreads();
  }

#pragma unroll
  for (int i = 0; i < 4; ++i) {
    float4 o4 = make_float4(acc[i][0], acc[i][1], acc[i][2], acc[i][3]);
    *(float4*)(C + (size_t)(m0 + ty * 4 + i) * N + n0 + tx * 4) = o4;
  }
}

// ---------------------------------------------------------------------------
// RoPE in-place on q and k slices of qkv [B][T][3C].
// One thread per (b,t,h,i) pair (i = freq index 0..31), handles q AND k.
// ---------------------------------------------------------------------------
__global__ __launch_bounds__(256) void rope_k(float* __restrict__ qkv,
                                              const float* __restrict__ fcos,
                                              const float* __restrict__ fsin) {
  int idx = blockIdx.x * 256 + threadIdx.x;   // 0 .. B*T*H*32-1
  int i = idx & 31;
  int h = (idx >> 5) & 15;
  int t = (idx >> 9) & 2047;
  int b = idx >> 20;
  float c = fcos[t * 32 + i];
  float s = fsin[t * 32 + i];
  size_t base = ((size_t)(b * T_ + t)) * F3_ + h * HD_ + 2 * i;
  // q
  float e = qkv[base], o = qkv[base + 1];
  qkv[base]     = e * c - o * s;
  qkv[base + 1] = e * s + o * c;
  // k
  float e2 = qkv[base + C_], o2 = qkv[base + C_ + 1];
  qkv[base + C_]     = e2 * c - o2 * s;
  qkv[base + C_ + 1] = e2 * s + o2 * c;
}

// ---------------------------------------------------------------------------
// Flash attention (causal), fp32.
// Block: 256 threads = 4 waves; Q-tile = 64 rows (wave w -> rows w*16..+15).
// K/V tiles of 64 keys staged in LDS, XOR-swizzled 16B chunks.
// Wave micro-layout: lane = (lg = lane>>4 row group, ll = lane&15).
//   QK scores: rows r = w*16+lg*4+i, keys kk = ll+16*j  (strided cols)
//   PV output: rows same, dims  d  = 4*ll+jd            (contiguous cols)
// ---------------------------------------------------------------------------
__device__ __forceinline__ float f4get(const float4& v, int t) {
  switch (t) { case 0: return v.x; case 1: return v.y; case 2: return v.z; default: return v.w; }
}

__global__ __launch_bounds__(256) void attn_k(const float* __restrict__ qkv,
                                              float* __restrict__ y) {
  __shared__ float Qs[64][64];        // swizzled
  __shared__ float Ks[64][64];        // swizzled
  __shared__ float Vs[64][64];        // swizzled
  __shared__ float Ps[4][16][64];     // per-wave P tile (logical layout)

  const int qt = 31 - blockIdx.y;     // heavy q-tiles first (better tail)
  const int bh = blockIdx.x;          // 0..31
  const int b = bh >> 4, h = bh & 15;
  const float* base = qkv + (size_t)b * T_ * F3_ + h * HD_;
  const int q0 = qt * 64;

  const int tid  = threadIdx.x;
  const int lane = tid & 63;
  const int w    = tid >> 6;
  const int lg   = lane >> 4;   // 0..3
  const int ll   = lane & 15;   // 0..15
  const float NEG_INF = -__builtin_inff();

  // stage Q tile once, pre-scaled by 1/sqrt(HD)
#pragma unroll
  for (int rep = 0; rep < 4; ++rep) {
    int idx4 = rep * 256 + tid;       // 0..1023 (float4 units)
    int r  = idx4 >> 4;               // 0..63
    int c4 = idx4 & 15;
    float4 v = *(const float4*)(base + (size_t)(q0 + r) * F3_ + c4 * 4);
    v.x *= 0.125f; v.y *= 0.125f; v.z *= 0.125f; v.w *= 0.125f;
    *(float4*)&Qs[r][(c4 ^ (r & 7)) << 2] = v;
  }

  float m[4], l[4], o[4][4];
#pragma unroll
  for (int i = 0; i < 4; ++i) {
    m[i] = NEG_INF; l[i] = 0.f;
#pragma unroll
    for (int j = 0; j < 4; ++j) o[i][j] = 0.f;
  }

  for (int kt = 0; kt <= qt; ++kt) {
    __syncthreads();   // previous tile fully consumed (also covers Q staging, iter 0)
    // stage K,V tiles (swizzled)
#pragma unroll
    for (int rep = 0; rep < 4; ++rep) {
      int idx4 = rep * 256 + tid;
      int r  = idx4 >> 4;
      int c4 = idx4 & 15;
      const float* row = base + (size_t)(kt * 64 + r) * F3_ + C_;
      float4 kv = *(const float4*)(row + c4 * 4);
      *(float4*)&Ks[r][(c4 ^ (r & 7)) << 2] = kv;
      float4 vv = *(const float4*)(row + C_ + c4 * 4);
      *(float4*)&Vs[r][(c4 ^ (r & 7)) << 2] = vv;
    }
    __syncthreads();

    // ---- QK^T: s[i][j], rows w*16+lg*4+i, keys ll+16*j ----
    float s[4][4] = {};
#pragma unroll 4
    for (int dc = 0; dc < 16; ++dc) {
      float4 qa[4], kb[4];
#pragma unroll
      for (int i = 0; i < 4; ++i) {
        int qr = w * 16 + lg * 4 + i;
        qa[i] = *(const float4*)&Qs[qr][(dc ^ (qr & 7)) << 2];
      }
#pragma unroll
      for (int j = 0; j < 4; ++j) {
        int kr = ll + 16 * j;
        kb[j] = *(const float4*)&Ks[kr][(dc ^ (kr & 7)) << 2];
      }
#pragma unroll
      for (int i = 0; i < 4; ++i)
#pragma unroll
        for (int j = 0; j < 4; ++j)
          s[i][j] += qa[i].x * kb[j].x + qa[i].y * kb[j].y +
                     qa[i].z * kb[j].z + qa[i].w * kb[j].w;
    }

    // causal mask on diagonal tile
    if (kt == qt) {
#pragma unroll
      for (int i = 0; i < 4; ++i) {
        int qr = w * 16 + lg * 4 + i;
#pragma unroll
        for (int j = 0; j < 4; ++j)
          if (ll + 16 * j > qr) s[i][j] = NEG_INF;
      }
    }

    // ---- online softmax per row ----
#pragma unroll
    for (int i = 0; i < 4; ++i) {
      float tmax = fmaxf(fmaxf(s[i][0], s[i][1]), fmaxf(s[i][2], s[i][3]));
#pragma unroll
      for (int off = 1; off < 16; off <<= 1)
        tmax = fmaxf(tmax, __shfl_xor(tmax, off));
      float mnew  = fmaxf(m[i], tmax);
      float alpha = __expf(m[i] - mnew);    // exp(-inf)=0 on first tile
      float psum = 0.f;
#pragma unroll
      for (int j = 0; j < 4; ++j) {
        float p = __expf(s[i][j] - mnew);
        s[i][j] = p;
        psum += p;
      }
#pragma unroll
      for (int off = 1; off < 16; off <<= 1)
        psum += __shfl_xor(psum, off);
      l[i] = l[i] * alpha + psum;
      m[i] = mnew;
#pragma unroll
      for (int jd = 0; jd < 4; ++jd) o[i][jd] *= alpha;
      // publish P (logical [row][key])
#pragma unroll
      for (int j = 0; j < 4; ++j)
        Ps[w][lg * 4 + i][ll + 16 * j] = s[i][j];
    }
    __syncthreads();   // P visible (and orders Vs reads vs next staging)

    // ---- PV: o[i][jd] += sum_jj P[r][jj] * V[jj][4*ll+jd] ----
#pragma unroll 4
    for (int jc = 0; jc < 16; ++jc) {
      float4 rp[4];
#pragma unroll
      for (int i = 0; i < 4; ++i)
        rp[i] = *(const float4*)&Ps[w][lg * 4 + i][jc * 4];
#pragma unroll
      for (int t = 0; t < 4; ++t) {
        int jj = jc * 4 + t;
        float4 rv = *(const float4*)&Vs[jj][(ll ^ (jj & 7)) << 2];
#pragma unroll
        for (int i = 0; i < 4; ++i) {
          float p = f4get(rp[i], t);
          o[i][0] += p * rv.x; o[i][1] += p * rv.y;
          o[i][2] += p * rv.z; o[i][3] += p * rv.w;
        }
      }
    }
  }

  // epilogue: y[b][q0+r][h*64 + 4*ll + jd] = o / l
#pragma unroll
  for (int i = 0; i < 4; ++i) {
    int qr = w * 16 + lg * 4 + i;
    float inv = 1.0f / l[i];
    float4 o4 = make_float4(o[i][0] * inv, o[i][1] * inv, o[i][2] * inv, o[i][3] * inv);
    *(float4*)(y + ((size_t)(b * T_ + q0 + qr)) * C_ + h * HD_ + ll * 4) = o4;
  }
}

// ---------------------------------------------------------------------------
extern "C" void kernel_launch(void* const* d_in, const int* in_sizes, int n_in,
                              void* d_out, int out_size, void* d_ws, size_t ws_size,
                              hipStream_t stream) {
  const float* x      = (const float*)d_in[0];
  const float* w_attn = (const float*)d_in[1];
  const float* w_proj = (const float*)d_in[2];
  const float* fcos   = (const float*)d_in[3];
  const float* fsin   = (const float*)d_in[4];
  float* out = (float*)d_out;

  const int M = B_ * T_;                   // 4096
  float* qkv = (float*)d_ws;               // M * 3072 floats = 50.3 MB
  float* y   = qkv + (size_t)M * F3_;      // M * 1024 floats = 16.8 MB

  // 1) QKV projection: qkv[m][f] = sum_c x[m][c] * w_attn[f][c]
  {
    dim3 grid(M / 64, F3_ / 64);
    gemm_bt_f32<<<grid, 256, 0, stream>>>(x, w_attn, qkv, M, F3_, C_);
  }
  // 2) RoPE on q,k
  {
    int total = B_ * T_ * H_ * (HD_ / 2);  // 2,097,152
    rope_k<<<total / 256, 256, 0, stream>>>(qkv, fcos, fsin);
  }
  // 3) causal flash attention -> y[m][c]
  {
    dim3 grid(B_ * H_, T_ / 64);
    attn_k<<<grid, 256, 0, stream>>>(qkv, y);
  }
  // 4) output projection: out[m][o] = sum_c y[m][c] * w_proj[o][c]
  {
    dim3 grid(M / 64, C_ / 64);
    gemm_bt_f32<<<grid, 256, 0, stream>>>(y, w_proj, out, M, C_, C_);
  }
}

// Round 2
// 138.352 us; speedup vs baseline: 6.0651x; 6.0651x over previous
//
#include <hip/hip_runtime.h>
#include <math.h>

#define B_  2
#define T_  2048
#define C_  1024
#define H_  16
#define HD_ 64
#define F3_ 3072   // 3*C

typedef __attribute__((ext_vector_type(8))) __bf16 bf16x8;
typedef __attribute__((ext_vector_type(4))) float  f32x4;

__device__ __forceinline__ ushort f2bf(float f) {
  uint32_t u = __builtin_bit_cast(uint32_t, f);
  u += 0x7fff + ((u >> 16) & 1);        // RNE
  return (ushort)(u >> 16);
}
__device__ __forceinline__ float bf2f(ushort u) {
  return __builtin_bit_cast(float, (uint32_t)u << 16);
}
// async global->LDS, 16B per lane; LDS dest = wave-uniform base + lane*16
__device__ __forceinline__ void gll16(void* lds, const void* g) {
  __builtin_amdgcn_global_load_lds(
      (const __attribute__((address_space(1))) void*)g,
      (__attribute__((address_space(3))) void*)lds, 16, 0, 0);
}

// ---------------------------------------------------------------------------
__global__ __launch_bounds__(256) void cvt_f32_bf16(const float* __restrict__ in,
                                                    ushort* __restrict__ out, int n4) {
  int i = blockIdx.x * 256 + threadIdx.x;
  if (i >= n4) return;
  float4 v = ((const float4*)in)[i];
  ushort4 o;
  o.x = f2bf(v.x); o.y = f2bf(v.y); o.z = f2bf(v.z); o.w = f2bf(v.w);
  ((ushort4*)out)[i] = o;
}

// ---------------------------------------------------------------------------
// bf16 MFMA GEMM, B^T weights: C[m][n] = sum_k A[m][k]*Bm[n][k].
// 128x128 tile, BK=64, 256 thr (2x2 waves, each 64x64 = 4x4 frags of 16x16).
// LDS linear [128][64] bf16, staged via global_load_lds w/ pre-swizzled global
// chunk (c = (lane&7)^(lane>>3)); ds_read applies the same XOR per row.
// MODE 0: write fp32 C.  MODE 1: qkv epilogue (q,k -> bf16 qkv; v -> vT).
// ---------------------------------------------------------------------------
template<int MODE>
__global__ __launch_bounds__(256) void gemm_mfma(
    const ushort* __restrict__ A, const ushort* __restrict__ Bm,
    void* __restrict__ Cout, ushort* __restrict__ vT,
    int M, int N, int K)
{
  __shared__ ushort As[128][64];
  __shared__ ushort Bs[128][64];
  const int tid  = threadIdx.x;
  const int lane = tid & 63, w = tid >> 6;
  const int wr = w >> 1, wc = w & 1;
  const int ll = lane & 15, lg = lane >> 4;
  const int r8 = lane >> 3;
  const int gc = ((lane & 7) ^ r8) << 3;   // swizzled global chunk offset (elems)
  const int m0 = blockIdx.x * 128, n0 = blockIdx.y * 128;

  f32x4 acc[4][4] = {};

  for (int k0 = 0; k0 < K; k0 += 64) {
    __syncthreads();
#pragma unroll
    for (int iss = 0; iss < 4; ++iss) {
      int rb = w * 32 + iss * 8;           // wave-uniform LDS row base
      gll16(&As[rb][0], A  + (size_t)(m0 + rb + r8) * K + k0 + gc);
      gll16(&Bs[rb][0], Bm + (size_t)(n0 + rb + r8) * K + k0 + gc);
    }
    __syncthreads();                        // drains vmcnt+lgkmcnt
#pragma unroll
    for (int ks = 0; ks < 2; ++ks) {
      const int sw = ((ks * 4 + lg) ^ (ll & 7)) * 8;
      bf16x8 af[4], bfr[4];
#pragma unroll
      for (int mi = 0; mi < 4; ++mi)
        af[mi] = *(const bf16x8*)&As[wr * 64 + mi * 16 + ll][sw];
#pragma unroll
      for (int ni = 0; ni < 4; ++ni)
        bfr[ni] = *(const bf16x8*)&Bs[wc * 64 + ni * 16 + ll][sw];
#pragma unroll
      for (int mi = 0; mi < 4; ++mi)
#pragma unroll
        for (int ni = 0; ni < 4; ++ni)
          acc[mi][ni] = __builtin_amdgcn_mfma_f32_16x16x32_bf16(
              af[mi], bfr[ni], acc[mi][ni], 0, 0, 0);
    }
  }

  // C/D layout (m89-verified): col = lane&15, row = (lane>>4)*4 + reg
  const int mrow = wr * 64 + lg * 4;
  const int ncol = wc * 64 + ll;
  if (MODE == 0) {
    float* C = (float*)Cout;
#pragma unroll
    for (int mi = 0; mi < 4; ++mi)
#pragma unroll
      for (int ni = 0; ni < 4; ++ni)
#pragma unroll
        for (int r = 0; r < 4; ++r)
          C[(size_t)(m0 + mrow + mi * 16 + r) * N + n0 + ncol + ni * 16] =
              acc[mi][ni][r];
  } else {
    if (n0 < 2 * C_) {                      // q,k region -> bf16 qkv
      ushort* q = (ushort*)Cout;
#pragma unroll
      for (int mi = 0; mi < 4; ++mi)
#pragma unroll
        for (int ni = 0; ni < 4; ++ni)
#pragma unroll
          for (int r = 0; r < 4; ++r)
            q[(size_t)(m0 + mrow + mi * 16 + r) * F3_ + n0 + ncol + ni * 16] =
                f2bf(acc[mi][ni][r]);
    } else {                                // v region -> vT[b][h][d][t]
      const int bb = m0 >> 11;
      const int tb = (m0 & 2047) + mrow;
#pragma unroll
      for (int mi = 0; mi < 4; ++mi)
#pragma unroll
        for (int ni = 0; ni < 4; ++ni) {
          int f  = n0 + ncol + ni * 16 - 2 * C_;
          int hh = f >> 6, d = f & 63;
          ushort4 o;
          o.x = f2bf(acc[mi][ni][0]); o.y = f2bf(acc[mi][ni][1]);
          o.z = f2bf(acc[mi][ni][2]); o.w = f2bf(acc[mi][ni][3]);
          *(ushort4*)&vT[(((size_t)(bb * H_ + hh) * HD_ + d) << 11) + tb + mi * 16] = o;
        }
    }
  }
}

// ---------------------------------------------------------------------------
// RoPE in-place on bf16 q,k; folds 1/sqrt(HD)=0.125 into q (exact pow2).
// One thread = 2 rotation pairs (ushort4 per q and k).
// ---------------------------------------------------------------------------
__global__ __launch_bounds__(256) void rope_bf(ushort* __restrict__ qkv,
                                               const float* __restrict__ fcos,
                                               const float* __restrict__ fsin) {
  int idx = blockIdx.x * 256 + threadIdx.x;   // B*T*H*16
  int i2 = idx & 15;
  int h  = (idx >> 4) & 15;
  int t  = (idx >> 8) & 2047;
  int b  = idx >> 19;
  int fi = t * 32 + i2 * 2;
  float c0 = fcos[fi], s0 = fsin[fi], c1 = fcos[fi + 1], s1 = fsin[fi + 1];
  size_t base = (size_t)(b * T_ + t) * F3_ + h * HD_ + i2 * 4;
  ushort4 qv = *(ushort4*)&qkv[base];
  ushort4 qo;
  { float e = bf2f(qv.x), o = bf2f(qv.y);
    qo.x = f2bf((e * c0 - o * s0) * 0.125f);
    qo.y = f2bf((e * s0 + o * c0) * 0.125f); }
  { float e = bf2f(qv.z), o = bf2f(qv.w);
    qo.z = f2bf((e * c1 - o * s1) * 0.125f);
    qo.w = f2bf((e * s1 + o * c1) * 0.125f); }
  *(ushort4*)&qkv[base] = qo;
  ushort4 kv = *(ushort4*)&qkv[base + C_];
  ushort4 ko;
  { float e = bf2f(kv.x), o = bf2f(kv.y);
    ko.x = f2bf(e * c0 - o * s0);
    ko.y = f2bf(e * s0 + o * c0); }
  { float e = bf2f(kv.z), o = bf2f(kv.w);
    ko.z = f2bf(e * c1 - o * s1);
    ko.w = f2bf(e * s1 + o * c1); }
  *(ushort4*)&qkv[base + C_] = ko;
}

// ---------------------------------------------------------------------------
// Flash attention, bf16 MFMA. 4 waves/block, 64 Q-rows (wave w -> 16 rows),
// KV tiles of 64. Q/K/VT staged via global_load_lds (swizzled chunks).
// Per wave per tile: 8 QK^T MFMAs + 8 PV MFMAs (16x16x32 bf16).
// P goes through padded LDS ([16][72], scalar-written -> padding legal).
// ---------------------------------------------------------------------------
__global__ __launch_bounds__(256) void attn_mfma(
    const ushort* __restrict__ qkv, const ushort* __restrict__ vT,
    ushort* __restrict__ y)
{
  __shared__ ushort Qs[64][64], Ks[64][64], VTs[64][64];
  __shared__ ushort Ps[4][16][72];

  const int qt = 31 - blockIdx.y;        // heavy tiles first
  const int bh = blockIdx.x;
  const int b = bh >> 4, h = bh & 15;
  const int q0 = qt * 64;
  const int tid = threadIdx.x, lane = tid & 63, w = tid >> 6;
  const int ll = lane & 15, lg = lane >> 4;
  const int r8 = lane >> 3;
  const int gc = ((lane & 7) ^ r8) << 3;
  const float NEG = -3.0e38f;

  const ushort* qb = qkv + (size_t)(b * T_) * F3_ + h * HD_;
  const ushort* kb = qb + C_;
  const ushort* vb = vT + ((size_t)(b * H_ + h) * HD_ << 11);

  // stage Q (once)
#pragma unroll
  for (int iss = 0; iss < 2; ++iss) {
    int rb = w * 16 + iss * 8;
    gll16(&Qs[rb][0], qb + (size_t)(q0 + rb + r8) * F3_ + gc);
  }
  __syncthreads();

  bf16x8 qf[2];
#pragma unroll
  for (int ks = 0; ks < 2; ++ks)
    qf[ks] = *(const bf16x8*)&Qs[w * 16 + ll][((ks * 4 + lg) ^ (ll & 7)) * 8];

  f32x4 oacc[4] = {};
  float m_[4], l_[4];
#pragma unroll
  for (int r = 0; r < 4; ++r) { m_[r] = NEG; l_[r] = 0.f; }

  for (int kt = 0; kt <= qt; ++kt) {
    __syncthreads();                      // prev K/V fully consumed
#pragma unroll
    for (int iss = 0; iss < 2; ++iss) {
      int rb = w * 16 + iss * 8;
      gll16(&Ks[rb][0],  kb + (size_t)(kt * 64 + rb + r8) * F3_ + gc);
      gll16(&VTs[rb][0], vb + ((size_t)(rb + r8) << 11) + kt * 64 + gc);
    }
    __syncthreads();

    // ---- S = QK^T : sacc[j] covers keys j*16+ll, rows lg*4+reg ----
    f32x4 sacc[4] = {};
#pragma unroll
    for (int ks = 0; ks < 2; ++ks) {
      const int sw = ((ks * 4 + lg) ^ (ll & 7)) * 8;
      bf16x8 kf[4];
#pragma unroll
      for (int j = 0; j < 4; ++j)
        kf[j] = *(const bf16x8*)&Ks[j * 16 + ll][sw];
#pragma unroll
      for (int j = 0; j < 4; ++j)
        sacc[j] = __builtin_amdgcn_mfma_f32_16x16x32_bf16(qf[ks], kf[j], sacc[j], 0, 0, 0);
    }

    if (kt == qt) {                       // causal mask on diagonal tile
#pragma unroll
      for (int j = 0; j < 4; ++j) {
        int key = j * 16 + ll;
#pragma unroll
        for (int r = 0; r < 4; ++r)
          if (key > w * 16 + lg * 4 + r) sacc[j][r] = NEG;
      }
    }

    // ---- online softmax (rows are lane-local per reg; reduce over 16 lanes)
#pragma unroll
    for (int r = 0; r < 4; ++r) {
      float tmax = fmaxf(fmaxf(sacc[0][r], sacc[1][r]), fmaxf(sacc[2][r], sacc[3][r]));
#pragma unroll
      for (int off = 1; off < 16; off <<= 1)
        tmax = fmaxf(tmax, __shfl_xor(tmax, off));
      float mnew = fmaxf(m_[r], tmax);
      float al = __expf(m_[r] - mnew);
      float p0 = __expf(sacc[0][r] - mnew);
      float p1 = __expf(sacc[1][r] - mnew);
      float p2 = __expf(sacc[2][r] - mnew);
      float p3 = __expf(sacc[3][r] - mnew);
      float ps = p0 + p1 + p2 + p3;
#pragma unroll
      for (int off = 1; off < 16; off <<= 1)
        ps += __shfl_xor(ps, off);
      l_[r] = l_[r] * al + ps;
      m_[r] = mnew;
#pragma unroll
      for (int dj = 0; dj < 4; ++dj) oacc[dj][r] *= al;
      int prow = lg * 4 + r;
      Ps[w][prow][ll]      = f2bf(p0);
      Ps[w][prow][16 + ll] = f2bf(p1);
      Ps[w][prow][32 + ll] = f2bf(p2);
      Ps[w][prow][48 + ll] = f2bf(p3);
    }

    // ---- O += P V ----
#pragma unroll
    for (int ks = 0; ks < 2; ++ks) {
      bf16x8 pf = *(const bf16x8*)&Ps[w][ll][ks * 32 + lg * 8];
      const int sw = ((ks * 4 + lg) ^ (ll & 7)) * 8;
#pragma unroll
      for (int dj = 0; dj < 4; ++dj) {
        bf16x8 vf = *(const bf16x8*)&VTs[dj * 16 + ll][sw];
        oacc[dj] = __builtin_amdgcn_mfma_f32_16x16x32_bf16(pf, vf, oacc[dj], 0, 0, 0);
      }
    }
  }

#pragma unroll
  for (int r = 0; r < 4; ++r) l_[r] = 1.f / l_[r];
#pragma unroll
  for (int dj = 0; dj < 4; ++dj)
#pragma unroll
    for (int r = 0; r < 4; ++r) {
      int row = q0 + w * 16 + lg * 4 + r;
      y[(size_t)(b * T_ + row) * C_ + h * HD_ + dj * 16 + ll] =
          f2bf(oacc[dj][r] * l_[r]);
    }
}

// ---------------------------------------------------------------------------
extern "C" void kernel_launch(void* const* d_in, const int* in_sizes, int n_in,
                              void* d_out, int out_size, void* d_ws, size_t ws_size,
                              hipStream_t stream) {
  const float* x      = (const float*)d_in[0];
  const float* w_attn = (const float*)d_in[1];
  const float* w_proj = (const float*)d_in[2];
  const float* fcos   = (const float*)d_in[3];
  const float* fsin   = (const float*)d_in[4];
  float* out = (float*)d_out;

  ushort* xb   = (ushort*)d_ws;                 // 4096x1024 bf16
  ushort* wab  = xb   + (size_t)4096 * 1024;    // 3072x1024
  ushort* wpb  = wab  + (size_t)3072 * 1024;    // 1024x1024
  ushort* qkvb = wpb  + (size_t)1024 * 1024;    // 4096x3072 (q,k only)
  ushort* vt   = qkvb + (size_t)4096 * 3072;    // [2][16][64][2048]
  ushort* yb   = vt   + (size_t)32 * 64 * 2048; // 4096x1024

  cvt_f32_bf16<<<4096, 256, 0, stream>>>(x,      xb,  1048576);
  cvt_f32_bf16<<<3072, 256, 0, stream>>>(w_attn, wab,  786432);
  cvt_f32_bf16<<<1024, 256, 0, stream>>>(w_proj, wpb,  262144);

  { dim3 g(32, 24); gemm_mfma<1><<<g, 256, 0, stream>>>(xb, wab, qkvb, vt, 4096, F3_, C_); }
  rope_bf<<<4096, 256, 0, stream>>>(qkvb, fcos, fsin);
  { dim3 g(32, 32); attn_mfma<<<g, 256, 0, stream>>>(qkvb, vt, yb); }
  { dim3 g(32, 8);  gemm_mfma<0><<<g, 256, 0, stream>>>(yb, wpb, out, nullptr, 4096, C_, C_); }
}

// Round 3
// 114.985 us; speedup vs baseline: 7.2977x; 1.2032x over previous
//
#include <hip/hip_runtime.h>
#include <math.h>

#define B_  2
#define T_  2048
#define C_  1024
#define H_  16
#define HD_ 64
#define F3_ 3072   // 3*C

typedef __attribute__((ext_vector_type(8))) __bf16 bf16x8;
typedef __attribute__((ext_vector_type(4))) float  f32x4;

__device__ __forceinline__ ushort f2bf(float f) {
  uint32_t u = __builtin_bit_cast(uint32_t, f);
  u += 0x7fff + ((u >> 16) & 1);        // RNE
  return (ushort)(u >> 16);
}
__device__ __forceinline__ float bf2f(ushort u) {
  return __builtin_bit_cast(float, (uint32_t)u << 16);
}
// async global->LDS, 16B per lane; LDS dest = wave-uniform base + lane*16
__device__ __forceinline__ void gll16(void* lds, const void* g) {
  __builtin_amdgcn_global_load_lds(
      (const __attribute__((address_space(1))) void*)g,
      (__attribute__((address_space(3))) void*)lds, 16, 0, 0);
}

// ---------------------------------------------------------------------------
__global__ __launch_bounds__(256) void cvt_f32_bf16(const float* __restrict__ in,
                                                    ushort* __restrict__ out, int n4) {
  int i = blockIdx.x * 256 + threadIdx.x;
  if (i >= n4) return;
  float4 v = ((const float4*)in)[i];
  ushort4 o;
  o.x = f2bf(v.x); o.y = f2bf(v.y); o.z = f2bf(v.z); o.w = f2bf(v.w);
  ((ushort4*)out)[i] = o;
}

// ---------------------------------------------------------------------------
// bf16 MFMA GEMM, B^T weights: C[m][n] = sum_k A[m][k]*Bm[n][k].
// 128x128 tile, BK=64, 256 thr (2x2 waves, each 64x64 = 4x4 frags of 16x16).
// MODE 0: write fp32 C.  MODE 1: qkv epilogue (q,k -> bf16 qkv; v -> vT).
// ---------------------------------------------------------------------------
template<int MODE>
__global__ __launch_bounds__(256) void gemm_mfma(
    const ushort* __restrict__ A, const ushort* __restrict__ Bm,
    void* __restrict__ Cout, ushort* __restrict__ vT,
    int M, int N, int K)
{
  __shared__ ushort As[128][64];
  __shared__ ushort Bs[128][64];
  const int tid  = threadIdx.x;
  const int lane = tid & 63, w = tid >> 6;
  const int wr = w >> 1, wc = w & 1;
  const int ll = lane & 15, lg = lane >> 4;
  const int r8 = lane >> 3;
  const int gc = ((lane & 7) ^ r8) << 3;   // swizzled global chunk offset (elems)
  const int m0 = blockIdx.x * 128, n0 = blockIdx.y * 128;

  f32x4 acc[4][4] = {};

  for (int k0 = 0; k0 < K; k0 += 64) {
    __syncthreads();
#pragma unroll
    for (int iss = 0; iss < 4; ++iss) {
      int rb = w * 32 + iss * 8;           // wave-uniform LDS row base
      gll16(&As[rb][0], A  + (size_t)(m0 + rb + r8) * K + k0 + gc);
      gll16(&Bs[rb][0], Bm + (size_t)(n0 + rb + r8) * K + k0 + gc);
    }
    __syncthreads();                        // drains vmcnt+lgkmcnt
#pragma unroll
    for (int ks = 0; ks < 2; ++ks) {
      const int sw = ((ks * 4 + lg) ^ (ll & 7)) * 8;
      bf16x8 af[4], bfr[4];
#pragma unroll
      for (int mi = 0; mi < 4; ++mi)
        af[mi] = *(const bf16x8*)&As[wr * 64 + mi * 16 + ll][sw];
#pragma unroll
      for (int ni = 0; ni < 4; ++ni)
        bfr[ni] = *(const bf16x8*)&Bs[wc * 64 + ni * 16 + ll][sw];
#pragma unroll
      for (int mi = 0; mi < 4; ++mi)
#pragma unroll
        for (int ni = 0; ni < 4; ++ni)
          acc[mi][ni] = __builtin_amdgcn_mfma_f32_16x16x32_bf16(
              af[mi], bfr[ni], acc[mi][ni], 0, 0, 0);
    }
  }

  // C/D layout: col = lane&15, row = (lane>>4)*4 + reg
  const int mrow = wr * 64 + lg * 4;
  const int ncol = wc * 64 + ll;
  if (MODE == 0) {
    float* C = (float*)Cout;
#pragma unroll
    for (int mi = 0; mi < 4; ++mi)
#pragma unroll
      for (int ni = 0; ni < 4; ++ni)
#pragma unroll
        for (int r = 0; r < 4; ++r)
          C[(size_t)(m0 + mrow + mi * 16 + r) * N + n0 + ncol + ni * 16] =
              acc[mi][ni][r];
  } else {
    if (n0 < 2 * C_) {                      // q,k region -> bf16 qkv
      ushort* q = (ushort*)Cout;
#pragma unroll
      for (int mi = 0; mi < 4; ++mi)
#pragma unroll
        for (int ni = 0; ni < 4; ++ni)
#pragma unroll
          for (int r = 0; r < 4; ++r)
            q[(size_t)(m0 + mrow + mi * 16 + r) * F3_ + n0 + ncol + ni * 16] =
                f2bf(acc[mi][ni][r]);
    } else {                                // v region -> vT[b][h][d][t]
      const int bb = m0 >> 11;
      const int tb = (m0 & 2047) + mrow;
#pragma unroll
      for (int mi = 0; mi < 4; ++mi)
#pragma unroll
        for (int ni = 0; ni < 4; ++ni) {
          int f  = n0 + ncol + ni * 16 - 2 * C_;
          int hh = f >> 6, d = f & 63;
          ushort4 o;
          o.x = f2bf(acc[mi][ni][0]); o.y = f2bf(acc[mi][ni][1]);
          o.z = f2bf(acc[mi][ni][2]); o.w = f2bf(acc[mi][ni][3]);
          *(ushort4*)&vT[(((size_t)(bb * H_ + hh) * HD_ + d) << 11) + tb + mi * 16] = o;
        }
    }
  }
}

// ---------------------------------------------------------------------------
// RoPE in-place on bf16 q,k; folds 1/sqrt(HD)=0.125 into q (exact pow2).
// ---------------------------------------------------------------------------
__global__ __launch_bounds__(256) void rope_bf(ushort* __restrict__ qkv,
                                               const float* __restrict__ fcos,
                                               const float* __restrict__ fsin) {
  int idx = blockIdx.x * 256 + threadIdx.x;   // B*T*H*16
  int i2 = idx & 15;
  int h  = (idx >> 4) & 15;
  int t  = (idx >> 8) & 2047;
  int b  = idx >> 19;
  int fi = t * 32 + i2 * 2;
  float c0 = fcos[fi], s0 = fsin[fi], c1 = fcos[fi + 1], s1 = fsin[fi + 1];
  size_t base = (size_t)(b * T_ + t) * F3_ + h * HD_ + i2 * 4;
  ushort4 qv = *(ushort4*)&qkv[base];
  ushort4 qo;
  { float e = bf2f(qv.x), o = bf2f(qv.y);
    qo.x = f2bf((e * c0 - o * s0) * 0.125f);
    qo.y = f2bf((e * s0 + o * c0) * 0.125f); }
  { float e = bf2f(qv.z), o = bf2f(qv.w);
    qo.z = f2bf((e * c1 - o * s1) * 0.125f);
    qo.w = f2bf((e * s1 + o * c1) * 0.125f); }
  *(ushort4*)&qkv[base] = qo;
  ushort4 kv = *(ushort4*)&qkv[base + C_];
  ushort4 ko;
  { float e = bf2f(kv.x), o = bf2f(kv.y);
    ko.x = f2bf(e * c0 - o * s0);
    ko.y = f2bf(e * s0 + o * c0); }
  { float e = bf2f(kv.z), o = bf2f(kv.w);
    ko.z = f2bf(e * c1 - o * s1);
    ko.w = f2bf(e * s1 + o * c1); }
  *(ushort4*)&qkv[base + C_] = ko;
}

// ---------------------------------------------------------------------------
// Flash attention, bf16 MFMA, swapped-QK^T in-lane softmax, dbuf K/V.
// 4 waves/block, 64 Q-rows (wave w -> rows w*16..+15), KV tiles of 64.
// QK^T computed as mfma(K,Q) -> S^T: lane holds 16 S-values of q-row (lane&15).
//   sacc[j][r] = S[key = j*16 + lg*4 + r][qrow = ll]
// Softmax fully per-lane (+2 shfl_xor across the 4 lane copies of a row).
// P: 4x ds_write_b64 -> Ps[16][72]; PV A-frag read = bf16x8 at [ll][ks*32+lg*8].
// O layout (unchanged): oacc[dj][r] = O[qrow=lg*4+r][dim=dj*16+ll].
// 2-phase pipeline: STAGE(next) -> compute(cur) -> barrier (drains).
// ---------------------------------------------------------------------------
__global__ __launch_bounds__(256) void attn_mfma(
    const ushort* __restrict__ qkv, const ushort* __restrict__ vT,
    ushort* __restrict__ y)
{
  __shared__ ushort Qs[64][64];
  __shared__ ushort Ks[2][64][64], VTs[2][64][64];
  __shared__ ushort Ps[4][16][72];

  const int qt = 31 - blockIdx.y;        // heavy tiles first
  const int bh = blockIdx.x;             // same bh -> same XCD (x-fastest rr)
  const int b = bh >> 4, h = bh & 15;
  const int q0 = qt * 64;
  const int tid = threadIdx.x, lane = tid & 63, w = tid >> 6;
  const int ll = lane & 15, lg = lane >> 4;
  const int r8 = lane >> 3;
  const int gc = ((lane & 7) ^ r8) << 3;
  const float NEG = -3.0e38f;

  const ushort* qb = qkv + (size_t)(b * T_) * F3_ + h * HD_;
  const ushort* kb = qb + C_;
  const ushort* vb = vT + ((size_t)(b * H_ + h) * HD_ << 11);

  // prologue: stage Q and K/V tile 0 into buf 0
#pragma unroll
  for (int iss = 0; iss < 2; ++iss) {
    int rb = w * 16 + iss * 8;
    gll16(&Qs[rb][0], qb + (size_t)(q0 + rb + r8) * F3_ + gc);
    gll16(&Ks[0][rb][0],  kb + (size_t)(rb + r8) * F3_ + gc);
    gll16(&VTs[0][rb][0], vb + ((size_t)(rb + r8) << 11) + gc);
  }
  __syncthreads();

  bf16x8 qf[2];
#pragma unroll
  for (int ks = 0; ks < 2; ++ks)
    qf[ks] = *(const bf16x8*)&Qs[w * 16 + ll][((ks * 4 + lg) ^ (ll & 7)) * 8];

  f32x4 oacc[4] = {};
  float m_ = NEG, l_ = 0.f;
  int cur = 0;

  for (int kt = 0; kt <= qt; ++kt) {
    // issue next tile's async loads (overlap with this tile's compute)
    if (kt < qt) {
#pragma unroll
      for (int iss = 0; iss < 2; ++iss) {
        int rb = w * 16 + iss * 8;
        gll16(&Ks[cur ^ 1][rb][0],
              kb + (size_t)((kt + 1) * 64 + rb + r8) * F3_ + gc);
        gll16(&VTs[cur ^ 1][rb][0],
              vb + ((size_t)(rb + r8) << 11) + (kt + 1) * 64 + gc);
      }
    }

    // ---- S^T = K Q^T ----
    f32x4 sacc[4] = {};
#pragma unroll
    for (int ks = 0; ks < 2; ++ks) {
      const int sw = ((ks * 4 + lg) ^ (ll & 7)) * 8;
      bf16x8 kf[4];
#pragma unroll
      for (int j = 0; j < 4; ++j)
        kf[j] = *(const bf16x8*)&Ks[cur][j * 16 + ll][sw];
#pragma unroll
      for (int j = 0; j < 4; ++j)
        sacc[j] = __builtin_amdgcn_mfma_f32_16x16x32_bf16(kf[j], qf[ks], sacc[j], 0, 0, 0);
    }

    if (kt == qt) {                       // causal mask on diagonal tile
#pragma unroll
      for (int j = 0; j < 4; ++j)
#pragma unroll
        for (int r = 0; r < 4; ++r)
          if (j * 16 + lg * 4 + r > w * 16 + ll) sacc[j][r] = NEG;
    }

    // ---- in-lane online softmax (row = ll; 4 lane-copies per row) ----
    float tmax;
    {
      float t0 = fmaxf(fmaxf(sacc[0][0], sacc[0][1]), fmaxf(sacc[0][2], sacc[0][3]));
      float t1 = fmaxf(fmaxf(sacc[1][0], sacc[1][1]), fmaxf(sacc[1][2], sacc[1][3]));
      float t2 = fmaxf(fmaxf(sacc[2][0], sacc[2][1]), fmaxf(sacc[2][2], sacc[2][3]));
      float t3 = fmaxf(fmaxf(sacc[3][0], sacc[3][1]), fmaxf(sacc[3][2], sacc[3][3]));
      tmax = fmaxf(fmaxf(t0, t1), fmaxf(t2, t3));
      tmax = fmaxf(tmax, __shfl_xor(tmax, 16));
      tmax = fmaxf(tmax, __shfl_xor(tmax, 32));
    }
    if (!__all(tmax <= m_ + 8.f)) {       // defer-max: rescale only on growth
      float mnew = fmaxf(m_, tmax);
      float al = __expf(m_ - mnew);       // 0 on first tile
      l_ *= al;
      m_ = mnew;
#pragma unroll
      for (int r = 0; r < 4; ++r) {
        float alr = __shfl(al, lg * 4 + r);
#pragma unroll
        for (int dj = 0; dj < 4; ++dj) oacc[dj][r] *= alr;
      }
    }
    float psum = 0.f;
#pragma unroll
    for (int j = 0; j < 4; ++j) {
      float p0 = __expf(sacc[j][0] - m_);
      float p1 = __expf(sacc[j][1] - m_);
      float p2 = __expf(sacc[j][2] - m_);
      float p3 = __expf(sacc[j][3] - m_);
      psum += (p0 + p1) + (p2 + p3);
      ushort4 pk;
      pk.x = f2bf(p0); pk.y = f2bf(p1); pk.z = f2bf(p2); pk.w = f2bf(p3);
      *(ushort4*)&Ps[w][ll][j * 16 + lg * 4] = pk;
    }
    psum += __shfl_xor(psum, 16);
    psum += __shfl_xor(psum, 32);
    l_ += psum;

    // ---- O += P V ----
#pragma unroll
    for (int ks = 0; ks < 2; ++ks) {
      bf16x8 pf = *(const bf16x8*)&Ps[w][ll][ks * 32 + lg * 8];
      const int sw = ((ks * 4 + lg) ^ (ll & 7)) * 8;
#pragma unroll
      for (int dj = 0; dj < 4; ++dj) {
        bf16x8 vf = *(const bf16x8*)&VTs[cur][dj * 16 + ll][sw];
        oacc[dj] = __builtin_amdgcn_mfma_f32_16x16x32_bf16(pf, vf, oacc[dj], 0, 0, 0);
      }
    }

    __syncthreads();   // drains next-stage vmcnt; all waves done with buf[cur]
    cur ^= 1;
  }

  // epilogue: broadcast l for rows lg*4+r, normalize, store bf16
#pragma unroll
  for (int r = 0; r < 4; ++r) {
    float lr = __shfl(l_, lg * 4 + r);
    float inv = 1.0f / lr;
    int row = q0 + w * 16 + lg * 4 + r;
#pragma unroll
    for (int dj = 0; dj < 4; ++dj)
      y[(size_t)(b * T_ + row) * C_ + h * HD_ + dj * 16 + ll] =
          f2bf(oacc[dj][r] * inv);
  }
}

// ---------------------------------------------------------------------------
extern "C" void kernel_launch(void* const* d_in, const int* in_sizes, int n_in,
                              void* d_out, int out_size, void* d_ws, size_t ws_size,
                              hipStream_t stream) {
  const float* x      = (const float*)d_in[0];
  const float* w_attn = (const float*)d_in[1];
  const float* w_proj = (const float*)d_in[2];
  const float* fcos   = (const float*)d_in[3];
  const float* fsin   = (const float*)d_in[4];
  float* out = (float*)d_out;

  ushort* xb   = (ushort*)d_ws;                 // 4096x1024 bf16
  ushort* wab  = xb   + (size_t)4096 * 1024;    // 3072x1024
  ushort* wpb  = wab  + (size_t)3072 * 1024;    // 1024x1024
  ushort* qkvb = wpb  + (size_t)1024 * 1024;    // 4096x3072 (q,k only)
  ushort* vt   = qkvb + (size_t)4096 * 3072;    // [2][16][64][2048]
  ushort* yb   = vt   + (size_t)32 * 64 * 2048; // 4096x1024

  cvt_f32_bf16<<<4096, 256, 0, stream>>>(x,      xb,  1048576);
  cvt_f32_bf16<<<3072, 256, 0, stream>>>(w_attn, wab,  786432);
  cvt_f32_bf16<<<1024, 256, 0, stream>>>(w_proj, wpb,  262144);

  { dim3 g(32, 24); gemm_mfma<1><<<g, 256, 0, stream>>>(xb, wab, qkvb, vt, 4096, F3_, C_); }
  rope_bf<<<4096, 256, 0, stream>>>(qkvb, fcos, fsin);
  { dim3 g(32, 32); attn_mfma<<<g, 256, 0, stream>>>(qkvb, vt, yb); }
  { dim3 g(32, 8);  gemm_mfma<0><<<g, 256, 0, stream>>>(yb, wpb, out, nullptr, 4096, C_, C_); }
}